// Round 5
// baseline (390.523 us; speedup 1.0000x reference)
//
#include <hip/hip_runtime.h>

// ---------------------------------------------------------------------------
// IntegerCifar10Net: 4-bit quantized CNN, B=512.
// Post-layer-1 math is EXACT integer arithmetic (acts 0..7, weights -7..7)
// on i8 MFMA (mfma_i32_16x16x64_i8). Layer 1 fp64-exact, weights via scalar
// loads (uniform address) -- no LDS weight reads. i8 convs: persistent blocks
// (weights staged once per block), act staging software-pipelined.
// Activations NHWC u8 (value = 7 * real). Epilogue fp64 affine+rint (proven
// bit-exact rounds 2-4).
// ---------------------------------------------------------------------------

typedef __attribute__((ext_vector_type(4))) int v4i;

// workspace offsets (bytes)
#define O_WD1    0u          // 13824   f64 conv1 [64][3][9]
#define O_QWF2   16384u      // 5120    i8 fc2 [10][512]
#define O_QWT2   24576u      // 36864   i8 [64][9][64]
#define O_QWT3   61440u      // 73728   i8 [128][9][64]
#define O_QWT4   135168u     // 147456  i8 [128][9][128]
#define O_QWT5   282624u     // 294912  i8 [256][9][128]
#define O_QWT6   577536u     // 589824  i8 [256][9][256]
#define O_QWF1   1167360u    // 2097152 i8 [512][4096] nhwc-k
#define O_BUFA   3264512u    // 33.5 MB
#define O_BUFB   36818944u   // 8.4 MB

// ---------------------------------------------------------------------------
// weight prep
// ---------------------------------------------------------------------------
__global__ void quantw_k(const float* __restrict__ w, signed char* __restrict__ q, int n) {
    int i = blockIdx.x * 256 + threadIdx.x;
    if (i < n) {
        double t = fmin(fmax((double)w[i], -1.0), 1.0) * 7.0;
        q[i] = (signed char)(int)rint(t);
    }
}

// conv1 weights: fp32 [64][3][9] -> f64 same order
__global__ void quantw1_f64_k(const float* __restrict__ w, double* __restrict__ o) {
    int i = blockIdx.x * 256 + threadIdx.x;
    if (i < 1728) {
        double t = fmin(fmax((double)w[i], -1.0), 1.0) * 7.0;
        o[i] = rint(t);
    }
}

// conv weights: fp32 [CO][CI][3][3] -> i8 [CO][9][CI]
__global__ void quantw_t8_k(const float* __restrict__ w, signed char* __restrict__ o,
                            int CI, int n) {
    int i = blockIdx.x * 256 + threadIdx.x;
    if (i < n) {
        int co  = i / (9 * CI);
        int rem = i - co * 9 * CI;
        int t   = rem / CI;
        int ci  = rem - t * CI;
        double v = fmin(fmax((double)w[(co * CI + ci) * 9 + t], -1.0), 1.0) * 7.0;
        o[i] = (signed char)(int)rint(v);
    }
}

// fc1 weights: fp32 [512][4096 nchw-k] -> i8 [512][4096 nhwc-k]
__global__ void quantw_fc1_k(const float* __restrict__ w, signed char* __restrict__ o) {
    int i = blockIdx.x * 256 + threadIdx.x;
    if (i < 512 * 4096) {
        int j  = i >> 12;
        int kn = i & 4095;
        int px = kn >> 8;
        int c  = kn & 255;
        int ko = c * 16 + px;
        double v = fmin(fmax((double)w[j * 4096 + ko], -1.0), 1.0) * 7.0;
        o[i] = (signed char)(int)rint(v);
    }
}

// ---------------------------------------------------------------------------
// conv1: 3->64, 32x32, fp64-exact. Weights via uniform (scalar) global loads;
// acts staged in LDS as doubles. NHWC u8 output.
// ---------------------------------------------------------------------------
__global__ __launch_bounds__(256) void conv1_k(
    const float* __restrict__ x, const double* __restrict__ wd,
    const float* __restrict__ gvec, const float* __restrict__ bvec,
    unsigned char* __restrict__ out)
{
    __shared__ double xs[3][10][35];

    const int tid  = threadIdx.x;
    const int sp   = tid & 63;
    const int cg   = __builtin_amdgcn_readfirstlane(tid >> 6);  // uniform wave id
    const int img  = blockIdx.x >> 2;
    const int slab = blockIdx.x & 3;
    const int y0s  = slab * 8;
    const int co_base = blockIdx.y * 16;
    const int co0  = co_base + cg * 4;   // uniform
    const int yb = sp >> 4, xb = sp & 15;
    const int ysl = yb * 2, x0 = xb * 2;

    for (int i = tid; i < 1020; i += 256) {
        int ci = i / 340, r = i - ci * 340;
        int ry = r / 34, rx = r - ry * 34;
        int gy = y0s - 1 + ry, gx = rx - 1;
        double v = 0.0;
        if ((unsigned)gy < 32u && (unsigned)gx < 32u)
            v = (double)x[(img * 3 + ci) * 1024 + gy * 32 + gx];
        xs[ci][ry][rx] = v;
    }
    __syncthreads();

    double acc[4][4];
#pragma unroll
    for (int l = 0; l < 4; ++l)
#pragma unroll
        for (int p = 0; p < 4; ++p) acc[l][p] = 0.0;

#pragma unroll
    for (int ci = 0; ci < 3; ++ci) {
        double a[4][4];
#pragma unroll
        for (int iy = 0; iy < 4; ++iy)
#pragma unroll
            for (int ix = 0; ix < 4; ++ix)
                a[iy][ix] = xs[ci][ysl + iy][x0 + ix];
#pragma unroll
        for (int l = 0; l < 4; ++l) {
            const double* wp = wd + ((co0 + l) * 3 + ci) * 9;  // uniform address
            double wr[9];
#pragma unroll
            for (int t = 0; t < 9; ++t) wr[t] = wp[t];
#pragma unroll
            for (int ky = 0; ky < 3; ++ky)
#pragma unroll
                for (int kx = 0; kx < 3; ++kx) {
                    const double wv = wr[ky * 3 + kx];
                    acc[l][0] = fma(wv, a[ky    ][kx    ], acc[l][0]);
                    acc[l][1] = fma(wv, a[ky    ][kx + 1], acc[l][1]);
                    acc[l][2] = fma(wv, a[ky + 1][kx    ], acc[l][2]);
                    acc[l][3] = fma(wv, a[ky + 1][kx + 1], acc[l][3]);
                }
        }
    }

#pragma unroll
    for (int l = 0; l < 4; ++l) {
        const int co = co0 + l;
        const double gg = (double)gvec[co];
        const double bb = (double)bvec[co];
#pragma unroll
        for (int p = 0; p < 4; ++p) {
            double conv = acc[l][p] / 7.0;
            double y = conv * gg + bb;
            double t = fmin(fmax(y, -1.0), 1.0) * 7.0;
            int q = (int)rint(t);
            q = q > 0 ? q : 0;
            const int Y = y0s + ysl + (p >> 1), X = x0 + (p & 1);
            out[((img * 32 + Y) * 32 + X) * 64 + co] = (unsigned char)q;
        }
    }
}

// ---------------------------------------------------------------------------
// i8 MFMA conv. Mode 1 (T>1, NPASS==1): persistent block over T px-tiles,
// weights staged once, act staging pipelined (prefetch t+1 before compute t).
// Mode 2 (T==1): acc persists over NPASS ci-chunks, next pass's acts+weights
// prefetched into regs during compute. LDS plane-split (conflict-free).
// ---------------------------------------------------------------------------
template<int CI, int CO, int H, int W, bool POOL, int IPB, int T>
__global__ __launch_bounds__(256, 2) void conv_i8_k(
    const unsigned char* __restrict__ in, const signed char* __restrict__ wt,
    const float* __restrict__ gvec, const float* __restrict__ bvec,
    unsigned char* __restrict__ out)
{
    constexpr int ATX    = (IPB == 1) ? 18 : 10;
    constexpr int APX    = ATX * ATX;
    constexpr int APLANE = IPB * APX * 16;
    constexpr int WBASE  = 4 * APLANE;
    constexpr int WPLANE = 576 * 16;
    constexpr int NPASS  = CI / 64;
    constexpr int AITEMS = IPB * APX * 4;
    constexpr int PFA    = (AITEMS + 255) / 256;
    constexpr int TPI    = (IPB == 1) ? (H / 16) * (W / 16) : 1;
    static_assert(T == 1 || NPASS == 1, "mode1 requires single pass");

    __shared__ __align__(16) char lds[WBASE + 4 * WPLANE];

    const int tid = threadIdx.x;
    const int l   = tid & 63;
    const int w   = tid >> 6;
    const int n   = l & 15;
    const int q   = l >> 4;
    const int co_base = blockIdx.y * 64;

    int wy8 = 0, wx8 = 0, tilepx = 0;
    if (IPB == 1) { wy8 = (w >> 1) * 8; wx8 = (w & 1) * 8; }
    else tilepx = w * APX;

    const int ly = ((n >> 3) & 1) * 2 + ((n >> 1) & 1);
    const int lx = ((n >> 2) & 1) * 2 + (n & 1);

    int abase[4], wbase[4];
#pragma unroll
    for (int ps = 0; ps < 4; ++ps) {
        int ay0 = wy8 + (ps >> 1) * 4 + ly;
        int ax0 = wx8 + (ps & 1) * 4 + lx;
        abase[ps] = q * APLANE + (tilepx + ay0 * ATX + ax0) * 16;
    }
#pragma unroll
    for (int cs = 0; cs < 4; ++cs)
        wbase[cs] = WBASE + q * WPLANE + ((cs * 16 + n) * 9) * 16;

    auto load_acts = [&](int gtile, int cib, uint4* pre) {
#pragma unroll
        for (int k = 0; k < PFA; ++k) {
            const int i = tid + k * 256;
            uint4 v = {0u, 0u, 0u, 0u};
            if (i < AITEMS) {
                const int px_g = i >> 2, c = i & 3;
                int tile = 0, px = px_g;
                if (IPB == 4) { tile = px_g / APX; px = px_g - tile * APX; }
                int regY0 = 0, regX0 = 0, bimg;
                if (IPB == 1) {
                    bimg = gtile / TPI;
                    int r = gtile % TPI;
                    regY0 = (r / (W / 16)) * 16;
                    regX0 = (r % (W / 16)) * 16;
                } else {
                    bimg = gtile * 4 + tile;
                }
                const int gy = regY0 - 1 + px / ATX;
                const int gx = regX0 - 1 + px % ATX;
                if ((unsigned)gy < (unsigned)H && (unsigned)gx < (unsigned)W)
                    v = *(const uint4*)&in[((bimg * H + gy) * W + gx) * CI + cib + c * 16];
            }
            pre[k] = v;
        }
    };
    auto write_acts = [&](const uint4* pre) {
#pragma unroll
        for (int k = 0; k < PFA; ++k) {
            const int i = tid + k * 256;
            if (i < AITEMS) {
                const int px_g = i >> 2, c = i & 3;
                *(uint4*)&lds[c * APLANE + px_g * 16] = pre[k];
            }
        }
    };
    auto load_w = [&](int cib, uint4* wpre) {
#pragma unroll
        for (int k = 0; k < 9; ++k) {
            const int i = tid + k * 256;
            const int row = i >> 2, c = i & 3;
            const int co_l = row / 9, tap = row - co_l * 9;
            wpre[k] = *(const uint4*)&wt[((co_base + co_l) * 9 + tap) * CI + cib + c * 16];
        }
    };
    auto write_w = [&](const uint4* wpre) {
#pragma unroll
        for (int k = 0; k < 9; ++k) {
            const int i = tid + k * 256;
            const int row = i >> 2, c = i & 3;
            *(uint4*)&lds[WBASE + c * WPLANE + row * 16] = wpre[k];
        }
    };
    auto compute = [&](v4i acc[4][4]) {
#pragma unroll
        for (int tap = 0; tap < 9; ++tap) {
            const int toff = ((tap / 3) * ATX + (tap % 3)) * 16;
            v4i bf[4], af[4];
#pragma unroll
            for (int cs = 0; cs < 4; ++cs)
                bf[cs] = *(const v4i*)&lds[wbase[cs] + tap * 16];
#pragma unroll
            for (int ps = 0; ps < 4; ++ps)
                af[ps] = *(const v4i*)&lds[abase[ps] + toff];
#pragma unroll
            for (int ps = 0; ps < 4; ++ps)
#pragma unroll
                for (int cs = 0; cs < 4; ++cs)
                    acc[ps][cs] = __builtin_amdgcn_mfma_i32_16x16x64_i8(
                        af[ps], bf[cs], acc[ps][cs], 0, 0, 0);
        }
    };
    auto epilogue = [&](v4i acc[4][4], int gtile) {
        int regY0 = 0, regX0 = 0, bimg;
        if (IPB == 1) {
            bimg = gtile / TPI;
            int r = gtile % TPI;
            regY0 = (r / (W / 16)) * 16;
            regX0 = (r % (W / 16)) * 16;
        } else bimg = gtile * 4 + w;
#pragma unroll
        for (int cs = 0; cs < 4; ++cs) {
            const int co = co_base + cs * 16 + n;
            const double gg = (double)gvec[co];
            const double bb = (double)bvec[co];
#pragma unroll
            for (int ps = 0; ps < 4; ++ps) {
                const int Yb = regY0 + wy8 + (ps >> 1) * 4 + (q >> 1) * 2;
                const int Xb = regX0 + wx8 + (ps & 1) * 4 + (q & 1) * 2;
                int r4[4];
#pragma unroll
                for (int r = 0; r < 4; ++r) {
                    double conv = (double)acc[ps][cs][r] / 49.0;
                    double y = conv * gg + bb;
                    double t = fmin(fmax(y, -1.0), 1.0) * 7.0;
                    int qi = (int)rint(t);
                    r4[r] = qi > 0 ? qi : 0;
                }
                if (POOL) {
                    int m = max(max(r4[0], r4[1]), max(r4[2], r4[3]));
                    out[((bimg * (H / 2) + (Yb >> 1)) * (W / 2) + (Xb >> 1)) * CO + co] = (unsigned char)m;
                } else {
#pragma unroll
                    for (int r = 0; r < 4; ++r) {
                        const int Y = Yb + (r >> 1), X = Xb + (r & 1);
                        out[((bimg * H + Y) * W + X) * CO + co] = (unsigned char)r4[r];
                    }
                }
            }
        }
    };

    if (T > 1) {
        // mode 1: persistent over T tiles, weights staged once
        uint4 wpre[9], pre[PFA];
        load_w(0, wpre);
        load_acts(blockIdx.x * T, 0, pre);
        write_w(wpre);
        write_acts(pre);
        __syncthreads();
        for (int t = 0; t < T; ++t) {
            const int gtile = blockIdx.x * T + t;
            if (t + 1 < T) load_acts(gtile + 1, 0, pre);   // prefetch
            v4i acc[4][4];
#pragma unroll
            for (int ps = 0; ps < 4; ++ps)
#pragma unroll
                for (int cs = 0; cs < 4; ++cs) acc[ps][cs] = (v4i)0;
            compute(acc);
            epilogue(acc, gtile);
            __syncthreads();
            if (t + 1 < T) { write_acts(pre); __syncthreads(); }
        }
    } else {
        // mode 2: acc persists over NPASS ci-chunks, prefetch next pass
        v4i acc[4][4];
#pragma unroll
        for (int ps = 0; ps < 4; ++ps)
#pragma unroll
            for (int cs = 0; cs < 4; ++cs) acc[ps][cs] = (v4i)0;
        uint4 wpre[9], pre[PFA];
        load_w(0, wpre);
        load_acts(blockIdx.x, 0, pre);
        write_w(wpre);
        write_acts(pre);
        __syncthreads();
        for (int p = 0; p < NPASS; ++p) {
            if (p + 1 < NPASS) {
                load_w((p + 1) * 64, wpre);
                load_acts(blockIdx.x, (p + 1) * 64, pre);
            }
            compute(acc);
            if (p + 1 < NPASS) {
                __syncthreads();
                write_w(wpre);
                write_acts(pre);
                __syncthreads();
            }
        }
        epilogue(acc, blockIdx.x);
    }
}

// ---------------------------------------------------------------------------
// FC1: h[512][4096] u8 x wt[512][4096] i8 -> u8 [512][512]
// ---------------------------------------------------------------------------
__global__ __launch_bounds__(256, 2) void fc1_i8_k(
    const unsigned char* __restrict__ h, const signed char* __restrict__ wt,
    const float* __restrict__ gvec, const float* __restrict__ bvec,
    unsigned char* __restrict__ out)
{
    __shared__ int red[4096];
    const int tid = threadIdx.x;
    const int l = tid & 63, w = tid >> 6;
    const int n = l & 15, q = l >> 4;
    const int m0 = blockIdx.x * 32, n0 = blockIdx.y * 32;

    v4i acc[2][2];
#pragma unroll
    for (int a = 0; a < 2; ++a)
#pragma unroll
        for (int b = 0; b < 2; ++b) acc[a][b] = (v4i)0;

    const int kb = w * 1024;
    for (int ks = 0; ks < 16; ++ks) {
        const int k = kb + ks * 64 + q * 16;
        v4i af[2], bf[2];
#pragma unroll
        for (int ms = 0; ms < 2; ++ms)
            af[ms] = *(const v4i*)&h[(m0 + ms * 16 + n) * 4096 + k];
#pragma unroll
        for (int ns = 0; ns < 2; ++ns)
            bf[ns] = *(const v4i*)&wt[(n0 + ns * 16 + n) * 4096 + k];
#pragma unroll
        for (int ms = 0; ms < 2; ++ms)
#pragma unroll
            for (int ns = 0; ns < 2; ++ns)
                acc[ms][ns] = __builtin_amdgcn_mfma_i32_16x16x64_i8(
                    af[ms], bf[ns], acc[ms][ns], 0, 0, 0);
    }

#pragma unroll
    for (int ms = 0; ms < 2; ++ms)
#pragma unroll
        for (int ns = 0; ns < 2; ++ns)
#pragma unroll
            for (int r = 0; r < 4; ++r)
                red[w * 1024 + (ms * 16 + q * 4 + r) * 32 + ns * 16 + n] = acc[ms][ns][r];
    __syncthreads();

#pragma unroll
    for (int j = 0; j < 4; ++j) {
        const int e = tid * 4 + j;
        int s = red[e] + red[1024 + e] + red[2048 + e] + red[3072 + e];
        const int ml = e >> 5, nl = e & 31;
        const int co = n0 + nl;
        double y = ((double)s / 49.0) * (double)gvec[co] + (double)bvec[co];
        double t = fmin(fmax(y, -1.0), 1.0) * 7.0;
        int qi = (int)rint(t);
        qi = qi > 0 ? qi : 0;
        out[(m0 + ml) * 512 + co] = (unsigned char)qi;
    }
}

// FC2
__global__ __launch_bounds__(256) void fc2_k(
    const unsigned char* __restrict__ h, const signed char* __restrict__ wq,
    const float* __restrict__ gvec, const float* __restrict__ bvec,
    float* __restrict__ out)
{
    const int gid = blockIdx.x * 256 + threadIdx.x;
    const int b = gid >> 4;
    const int n = gid & 15;
    if (b >= 512 || n >= 10) return;
    int s = 0;
    for (int k = 0; k < 512; ++k)
        s += (int)h[b * 512 + k] * (int)wq[n * 512 + k];
    double y = ((double)s / 49.0) * (double)gvec[n] + (double)bvec[n];
    double t = fmin(fmax(y, -1.0), 1.0) * 7.0;
    double r = rint(t);
    out[b * 10 + n] = (float)(r / 7.0);
}

// ---------------------------------------------------------------------------
extern "C" void kernel_launch(void* const* d_in, const int* in_sizes, int n_in,
                              void* d_out, int out_size, void* d_ws, size_t ws_size,
                              hipStream_t stream) {
    const float* x   = (const float*)d_in[0];
    const float* w1  = (const float*)d_in[1];
    const float* g1  = (const float*)d_in[2];
    const float* b1  = (const float*)d_in[3];
    const float* w2  = (const float*)d_in[4];
    const float* g2  = (const float*)d_in[5];
    const float* b2  = (const float*)d_in[6];
    const float* w3  = (const float*)d_in[7];
    const float* g3  = (const float*)d_in[8];
    const float* b3  = (const float*)d_in[9];
    const float* w4  = (const float*)d_in[10];
    const float* g4  = (const float*)d_in[11];
    const float* b4  = (const float*)d_in[12];
    const float* w5  = (const float*)d_in[13];
    const float* g5  = (const float*)d_in[14];
    const float* b5  = (const float*)d_in[15];
    const float* w6  = (const float*)d_in[16];
    const float* g6  = (const float*)d_in[17];
    const float* b6  = (const float*)d_in[18];
    const float* wf1 = (const float*)d_in[19];
    const float* gf1 = (const float*)d_in[20];
    const float* bf1 = (const float*)d_in[21];
    const float* wf2 = (const float*)d_in[22];
    const float* gf2 = (const float*)d_in[23];
    const float* bf2 = (const float*)d_in[24];

    char* ws = (char*)d_ws;
    double*        wd1  = (double*)(ws + O_WD1);
    signed char*   qwf2 = (signed char*)(ws + O_QWF2);
    signed char*   qwt2 = (signed char*)(ws + O_QWT2);
    signed char*   qwt3 = (signed char*)(ws + O_QWT3);
    signed char*   qwt4 = (signed char*)(ws + O_QWT4);
    signed char*   qwt5 = (signed char*)(ws + O_QWT5);
    signed char*   qwt6 = (signed char*)(ws + O_QWT6);
    signed char*   qwf1 = (signed char*)(ws + O_QWF1);
    unsigned char* bufA = (unsigned char*)(ws + O_BUFA);
    unsigned char* bufB = (unsigned char*)(ws + O_BUFB);

    // weight prep
    hipLaunchKernelGGL(quantw1_f64_k, dim3(7), dim3(256), 0, stream, w1, wd1);
    hipLaunchKernelGGL(quantw_k, dim3(20), dim3(256), 0, stream, wf2, qwf2, 5120);
    hipLaunchKernelGGL(quantw_t8_k, dim3(144),  dim3(256), 0, stream, w2, qwt2, 64,  36864);
    hipLaunchKernelGGL(quantw_t8_k, dim3(288),  dim3(256), 0, stream, w3, qwt3, 64,  73728);
    hipLaunchKernelGGL(quantw_t8_k, dim3(576),  dim3(256), 0, stream, w4, qwt4, 128, 147456);
    hipLaunchKernelGGL(quantw_t8_k, dim3(1152), dim3(256), 0, stream, w5, qwt5, 128, 294912);
    hipLaunchKernelGGL(quantw_t8_k, dim3(2304), dim3(256), 0, stream, w6, qwt6, 256, 589824);
    hipLaunchKernelGGL(quantw_fc1_k, dim3(8192), dim3(256), 0, stream, wf1, qwf1);

    // conv stack
    hipLaunchKernelGGL(conv1_k, dim3(2048, 4), dim3(256), 0, stream, x, wd1, g1, b1, bufA);
    hipLaunchKernelGGL((conv_i8_k<64,  64,  32, 32, true,  1, 4>), dim3(512, 1), dim3(256), 0, stream, bufA, qwt2, g2, b2, bufB);
    hipLaunchKernelGGL((conv_i8_k<64,  128, 16, 16, false, 1, 2>), dim3(256, 2), dim3(256), 0, stream, bufB, qwt3, g3, b3, bufA);
    hipLaunchKernelGGL((conv_i8_k<128, 128, 16, 16, true,  1, 1>), dim3(512, 2), dim3(256), 0, stream, bufA, qwt4, g4, b4, bufB);
    hipLaunchKernelGGL((conv_i8_k<128, 256, 8,  8,  false, 4, 1>), dim3(128, 4), dim3(256), 0, stream, bufB, qwt5, g5, b5, bufA);
    hipLaunchKernelGGL((conv_i8_k<256, 256, 8,  8,  true,  4, 1>), dim3(128, 4), dim3(256), 0, stream, bufA, qwt6, g6, b6, bufB);

    // FC head
    hipLaunchKernelGGL(fc1_i8_k, dim3(16, 16), dim3(256), 0, stream, bufB, qwf1, gf1, bf1, bufA);
    hipLaunchKernelGGL(fc2_k, dim3(32), dim3(256), 0, stream, bufA, qwf2, gf2, bf2, (float*)d_out);
}